// Round 4
// baseline (7162.487 us; speedup 1.0000x reference)
//
#include <hip/hip_runtime.h>
#include <hip/hip_bf16.h>

typedef __attribute__((ext_vector_type(8))) short short8;
typedef __attribute__((ext_vector_type(4))) float floatx4;
typedef __attribute__((ext_vector_type(4))) unsigned short ushort4v;

#define NQ 512
#define NH 100000
#define DM 256
#define BH 64
#define BQ 128

#define MFMA_BF16(a, b, c) __builtin_amdgcn_mfma_f32_16x16x32_bf16((a), (b), (c), 0, 0, 0)

__device__ __forceinline__ unsigned short f2bf(float f) {
    union { float f; unsigned u; } v; v.f = f;
    unsigned u = v.u + 0x7fffu + ((v.u >> 16) & 1u);   // round-to-nearest-even
    return (unsigned short)(u >> 16);
}

// XOR-swizzled LDS index helpers (ushort units). XOR hits element bits 3..5
// (16B slots) -> 16B alignment preserved; reads land 2-way per bank (free).
__device__ __forceinline__ int kidx(int h, int d) { return (h * 256 + d) ^ ((h & 7) << 3); }  // K[64][256]
__device__ __forceinline__ int vidx(int d, int h) { return (d * 64 + h) ^ ((d & 7) << 3); }   // V^T[256][64]
__device__ __forceinline__ int widx(int q, int h) { return (q * 64 + h) ^ ((q & 7) << 3); }   // w[128][64]

// ---- issue tile K/V loads into registers (no conversion, no waits) ----
__device__ __forceinline__ void issue_kv(const float* __restrict__ Kg,
                                         const float* __restrict__ Vg,
                                         long hb, int tid,
                                         floatx4* kreg, float* vreg)
{
    const int khr = tid >> 3, kd0 = (tid & 7) * 4;
    long krow = hb + khr; if (krow > (long)NH - 1) krow = (long)NH - 1;
    const float* kp = Kg + (size_t)krow * DM;
#pragma unroll
    for (int c = 0; c < 8; ++c) kreg[c] = *(const floatx4*)(kp + kd0 + 32 * c);

    const int vd = tid & 63, vh0 = tid >> 6;
#pragma unroll
    for (int jh = 0; jh < 2; ++jh)
#pragma unroll
        for (int r = 0; r < 4; ++r) {
            long vrow = hb + 4 * (vh0 + 8 * jh) + r; if (vrow > (long)NH - 1) vrow = (long)NH - 1;
            const float* vp = Vg + (size_t)vrow * DM + vd;
#pragma unroll
            for (int jd = 0; jd < 4; ++jd)
                vreg[jh * 16 + jd * 4 + r] = vp[64 * jd];
        }
}

// ---- convert prefetched registers and write into LDS buffers ----
__device__ __forceinline__ void write_kv(unsigned short* Kb, unsigned short* Vb,
                                         int tid, const floatx4* kreg, const float* vreg)
{
    const int khr = tid >> 3, kd0 = (tid & 7) * 4;
#pragma unroll
    for (int c = 0; c < 8; ++c) {
        floatx4 v = kreg[c];
        ushort4v p;
        p[0] = f2bf(v[0]); p[1] = f2bf(v[1]); p[2] = f2bf(v[2]); p[3] = f2bf(v[3]);
        *(ushort4v*)&Kb[kidx(khr, kd0 + 32 * c)] = p;
    }
    const int vd = tid & 63, vh0 = tid >> 6;
#pragma unroll
    for (int jh = 0; jh < 2; ++jh)
#pragma unroll
        for (int jd = 0; jd < 4; ++jd) {
            ushort4v p;
#pragma unroll
            for (int r = 0; r < 4; ++r) p[r] = f2bf(vreg[jh * 16 + jd * 4 + r]);
            *(ushort4v*)&Vb[vidx(vd + 64 * jd, 4 * (vh0 + 8 * jh))] = p;
        }
}

__global__ __launch_bounds__(512)
void maskattn_phase1(const float* __restrict__ Qg,
                     const float* __restrict__ Kg,
                     const float* __restrict__ Vg,
                     const float* __restrict__ Mg,
                     float* __restrict__ numW,
                     float* __restrict__ denW,
                     int CH)
{
    __shared__ __attribute__((aligned(16))) unsigned short K_lds[2][64 * 256];  // 2 x 32 KB
    __shared__ __attribute__((aligned(16))) unsigned short V_lds[2][64 * 256];  // 2 x 32 KB, [d][h]
    __shared__ __attribute__((aligned(16))) unsigned short w_lds[128 * 64];     // 16 KB

    const int tid  = threadIdx.x;
    const int lane = tid & 63;
    const int wid  = tid >> 6;     // 0..7
    const int wm   = wid >> 1;     // 0..3 : q rows 32*wm..+31 (block-local)
    const int wn   = wid & 1;      // 0..1 : S h-half / PV d-half
    const int g    = lane >> 4;    // 0..3
    const int l15  = lane & 15;

    // Natural mapping (R0-proven L2/LLC behavior): the 4 q-tile sharers of a
    // chunk have consecutive blockIdx -> dispatched ~simultaneously.
    const int qt    = blockIdx.x & 3;
    const int hc    = blockIdx.x >> 2;
    const int qbase = qt * BQ;
    const long h0   = (long)hc * CH;
    const long hEnd = (h0 + CH < (long)NH) ? (h0 + CH) : (long)NH;
    const int qrow0 = qbase + 32 * wm;

    // ---- Q fragments in registers: A[row=l15][k=8*g+i], d = 32*ks + 8*g + i ----
    short8 qa[2][8];
#pragma unroll
    for (int fq = 0; fq < 2; ++fq) {
        const float* qp = Qg + (size_t)(qrow0 + 16 * fq + l15) * DM + 8 * g;
#pragma unroll
        for (int ks = 0; ks < 8; ++ks) {
            floatx4 a = *(const floatx4*)(qp + 32 * ks);
            floatx4 b = *(const floatx4*)(qp + 32 * ks + 4);
            short8 fr;
            fr[0]=(short)f2bf(a[0]); fr[1]=(short)f2bf(a[1]);
            fr[2]=(short)f2bf(a[2]); fr[3]=(short)f2bf(a[3]);
            fr[4]=(short)f2bf(b[0]); fr[5]=(short)f2bf(b[1]);
            fr[6]=(short)f2bf(b[2]); fr[7]=(short)f2bf(b[3]);
            qa[fq][ks] = fr;
        }
    }

    floatx4 acc[2][8];
#pragma unroll
    for (int i = 0; i < 2; ++i)
#pragma unroll
        for (int j = 0; j < 8; ++j) { floatx4 z = {0.f,0.f,0.f,0.f}; acc[i][j] = z; }
    float dacc[8];
#pragma unroll
    for (int i = 0; i < 8; ++i) dacc[i] = 0.f;

    const int ntiles = (hEnd > h0) ? (int)((hEnd - h0 + BH - 1) / BH) : 0;

    if (ntiles > 0) {
        floatx4 kreg[8];
        float   vreg[32];
        float   mcur[16];

        // ---- prologue: stage tile 0 ----
        issue_kv(Kg, Vg, h0, tid, kreg, vreg);
        write_kv(K_lds[0], V_lds[0], tid, kreg, vreg);
        __syncthreads();

        int cur = 0;
        for (int t = 0; t < ntiles; ++t) {
            const long hb = h0 + (long)t * BH;
            const bool pf = (t + 1 < ntiles);

            // ---- mask(t) issued FIRST (w-phase's counted vmcnt drains only these) ----
#pragma unroll
            for (int fn = 0; fn < 2; ++fn) {
                long h = hb + 32 * wn + 16 * fn + l15; if (h > (long)NH - 1) h = (long)NH - 1;
#pragma unroll
                for (int fq = 0; fq < 2; ++fq)
#pragma unroll
                    for (int j = 0; j < 4; ++j)
                        mcur[fn * 8 + fq * 4 + j] = Mg[(size_t)(qrow0 + 16 * fq + 4 * g + j) * NH + h];
            }
            // ---- issue tile t+1 K/V loads (in flight across the whole compute) ----
            if (pf) issue_kv(Kg, Vg, hb + BH, tid, kreg, vreg);

            // ---- S = Q K^T on buffer cur: wave computes 32q x 32h ----
            const unsigned short* Kc = K_lds[cur];
            floatx4 sf[2][2];
            { floatx4 z = {0.f,0.f,0.f,0.f}; sf[0][0]=z; sf[0][1]=z; sf[1][0]=z; sf[1][1]=z; }
#pragma unroll
            for (int ks = 0; ks < 8; ++ks) {
                short8 kb0 = *(const short8*)&Kc[kidx(32 * wn +      l15, 32 * ks + 8 * g)];
                short8 kb1 = *(const short8*)&Kc[kidx(32 * wn + 16 + l15, 32 * ks + 8 * g)];
                sf[0][0] = MFMA_BF16(qa[0][ks], kb0, sf[0][0]);
                sf[0][1] = MFMA_BF16(qa[0][ks], kb1, sf[0][1]);
                sf[1][0] = MFMA_BF16(qa[1][ks], kb0, sf[1][0]);
                sf[1][1] = MFMA_BF16(qa[1][ks], kb1, sf[1][1]);
            }

            // ---- w = mask * exp(s/16) ----
#pragma unroll
            for (int fn = 0; fn < 2; ++fn) {
                const long h = hb + 32 * wn + 16 * fn + l15;
                const bool valid = (h < hEnd);
#pragma unroll
                for (int fq = 0; fq < 2; ++fq)
#pragma unroll
                    for (int j = 0; j < 4; ++j) {
                        const int rloc = 32 * wm + 16 * fq + 4 * g + j;
                        float m = valid ? mcur[fn * 8 + fq * 4 + j] : 0.f;
                        float s = sf[fq][fn][j] * 0.0625f;
                        s = (s > 60.f) ? 60.f : s;
                        float w = m * __expf(s);
                        dacc[fq * 4 + j] += w;
                        w_lds[widx(rloc, 32 * wn + 16 * fn + l15)] = f2bf(w);
                    }
            }
            __syncthreads();

            // ---- PV on buffer cur: out(32q x 128d per wave) ----
            const unsigned short* Vc = V_lds[cur];
#pragma unroll
            for (int ks = 0; ks < 2; ++ks) {
                short8 wa0 = *(const short8*)&w_lds[widx(32 * wm +      l15, 32 * ks + 8 * g)];
                short8 wa1 = *(const short8*)&w_lds[widx(32 * wm + 16 + l15, 32 * ks + 8 * g)];
#pragma unroll
                for (int fd = 0; fd < 8; ++fd) {
                    short8 vb = *(const short8*)&Vc[vidx(128 * wn + 16 * fd + l15, 32 * ks + 8 * g)];
                    acc[0][fd] = MFMA_BF16(wa0, vb, acc[0][fd]);
                    acc[1][fd] = MFMA_BF16(wa1, vb, acc[1][fd]);
                }
            }

            // ---- drain prefetch into the other buffer ----
            if (pf) write_kv(K_lds[cur ^ 1], V_lds[cur ^ 1], tid, kreg, vreg);
            __syncthreads();
            cur ^= 1;
        }
    }

    // ---- den: reduce 16 h-lanes per row; combine wn halves via LDS ----
    __syncthreads();
    float* dshare = (float*)w_lds;   // w_lds dead now
#pragma unroll
    for (int r = 0; r < 8; ++r) {
        float v = dacc[r];
        v += __shfl_xor(v, 1);
        v += __shfl_xor(v, 2);
        v += __shfl_xor(v, 4);
        v += __shfl_xor(v, 8);
        if (l15 == 0) {
            const int fq = r >> 2, j = r & 3;
            dshare[wn * 128 + 32 * wm + 16 * fq + 4 * g + j] = v;
        }
    }
    __syncthreads();
    if (tid < BQ) {
        denW[(size_t)hc * NQ + qbase + tid] = dshare[tid] + dshare[128 + tid];
    }

    // ---- num partial write ----
#pragma unroll
    for (int fq = 0; fq < 2; ++fq)
#pragma unroll
        for (int fd = 0; fd < 8; ++fd)
#pragma unroll
            for (int j = 0; j < 4; ++j) {
                const int qrow = qbase + 32 * wm + 16 * fq + 4 * g + j;
                const int d    = 128 * wn + 16 * fd + l15;
                numW[((size_t)hc * NQ + qrow) * DM + d] = acc[fq][fd][j];
            }
}

__global__ void maskattn_reduce(const float* __restrict__ numW,
                                const float* __restrict__ denW,
                                float* __restrict__ out, int C)
{
    const int q = blockIdx.x;
    const int d = threadIdx.x;
    float sn = 0.f, sd = 0.f;
    for (int c = 0; c < C; ++c) {
        sn += numW[((size_t)c * NQ + q) * DM + d];
        sd += denW[(size_t)c * NQ + q];
    }
    out[(size_t)q * DM + d] = sn / sd;
}

extern "C" void kernel_launch(void* const* d_in, const int* in_sizes, int n_in,
                              void* d_out, int out_size, void* d_ws, size_t ws_size,
                              hipStream_t stream)
{
    const float* Qg = (const float*)d_in[0];
    const float* Kg = (const float*)d_in[1];
    const float* Vg = (const float*)d_in[2];
    const float* Mg = (const float*)d_in[3];
    float* out = (float*)d_out;

    const size_t per_chunk = (size_t)NQ * DM * sizeof(float) + (size_t)NQ * sizeof(float);
    int C = (int)(ws_size / per_chunk);
    if (C > 64) C = 64;
    float* numW;
    float* denW;
    if (C >= 1) {
        numW = (float*)d_ws;
        denW = numW + (size_t)C * NQ * DM;
    } else {
        C = 1;
        numW = out;                  // emergency fallback
        denW = (float*)d_ws;
    }
    const int ch64 = (NH + 64 * C - 1) / (64 * C);
    const int CH = 64 * ch64;

    maskattn_phase1<<<dim3((NQ / BQ) * C), dim3(512), 0, stream>>>(Qg, Kg, Vg, Mg, numW, denW, CH);
    maskattn_reduce<<<dim3(NQ), dim3(DM), 0, stream>>>(numW, denW, out, C);
}

// Round 5
// 488.893 us; speedup vs baseline: 14.6504x; 14.6504x over previous
//
#include <hip/hip_runtime.h>
#include <hip/hip_bf16.h>

typedef __attribute__((ext_vector_type(8))) short short8;
typedef __attribute__((ext_vector_type(4))) float floatx4;

#define NQ 512
#define NH 100000
#define DM 256
#define BH 32
#define BQ 128
#define WSTR 48   // w row stride (ushort): 96B rows -> 16B aligned, 24-bank step

#define MFMA_BF16(a, b, c) __builtin_amdgcn_mfma_f32_16x16x32_bf16((a), (b), (c), 0, 0, 0)

__device__ __forceinline__ unsigned short f2bf(float f) {
    union { float f; unsigned u; } v; v.f = f;
    unsigned u = v.u + 0x7fffu + ((v.u >> 16) & 1u);   // round-to-nearest-even
    return (unsigned short)(u >> 16);
}

// Row-dependent XOR swizzle (f32-element units, 4-elem=16B granularity).
// Applied on the GLOBAL source of global_load_lds (LDS dest must be linear),
// and on every LDS read: lds[h*DM + (d ^ vswz4(h))] == K[h][d].
__device__ __forceinline__ int vswz4(int r) { return (((r & 7) ^ ((r >> 3) & 3)) << 2); }

__device__ __forceinline__ void gload_lds16(const float* g, float* l) {
    __builtin_amdgcn_global_load_lds((const __attribute__((address_space(1))) void*)g,
                                     (__attribute__((address_space(3))) void*)l,
                                     16, 0, 0);
}

// Stage one BH x DM f32 tile pair (K,V) async into LDS. Zero registers held.
// Wave wid<4 -> K rows 8*wid..+7 ; wid>=4 -> V rows. One 1KB row per instr.
__device__ __forceinline__ void stage_tile_async(const float* __restrict__ Kg,
                                                 const float* __restrict__ Vg,
                                                 long hb, int wid, int lane,
                                                 float* Kbuf, float* Vbuf)
{
    const bool isK = (wid < 4);
    const int r0 = (wid & 3) * 8;
    const float* src = isK ? Kg : Vg;
    float* dst = isK ? Kbuf : Vbuf;
#pragma unroll
    for (int rr = 0; rr < 8; ++rr) {
        const int r = r0 + rr;
        long grow = hb + r; if (grow > (long)NH - 1) grow = (long)NH - 1;
        const float* gp = src + (size_t)grow * DM + ((4 * lane) ^ vswz4(r));
        gload_lds16(gp, dst + r * DM);
    }
}

__global__ __launch_bounds__(512, 2)
void maskattn_phase1(const float* __restrict__ Qg,
                     const float* __restrict__ Kg,
                     const float* __restrict__ Vg,
                     const float* __restrict__ Mg,
                     float* __restrict__ numW,
                     float* __restrict__ denW,
                     int CH)
{
    __shared__ __attribute__((aligned(16))) float K_lds[2][BH * DM];        // 2 x 32 KB
    __shared__ __attribute__((aligned(16))) float V_lds[2][BH * DM];        // 2 x 32 KB
    __shared__ __attribute__((aligned(16))) unsigned short w_lds[BQ * WSTR]; // 12 KB

    const int tid  = threadIdx.x;
    const int lane = tid & 63;
    const int wid  = tid >> 6;     // 0..7
    const int wm   = wid >> 1;     // 0..3 : q rows 32*wm..+31 (block-local)
    const int wn   = wid & 1;      // 0..1 : S h-half (16) / PV d-half (128)
    const int g    = lane >> 4;    // 0..3
    const int l15  = lane & 15;

    const int qt    = blockIdx.x & 3;
    const int hc    = blockIdx.x >> 2;
    const int qbase = qt * BQ;
    const long h0   = (long)hc * CH;
    const long hEnd = (h0 + CH < (long)NH) ? (h0 + CH) : (long)NH;
    const int qrow0 = qbase + 32 * wm;

    // ---- Q fragments in registers: A[row=l15][k=8*g+i], d = 32*ks + 8*g + i ----
    short8 qa[2][8];
#pragma unroll
    for (int fq = 0; fq < 2; ++fq) {
        const float* qp = Qg + (size_t)(qrow0 + 16 * fq + l15) * DM + 8 * g;
#pragma unroll
        for (int ks = 0; ks < 8; ++ks) {
            floatx4 a = *(const floatx4*)(qp + 32 * ks);
            floatx4 b = *(const floatx4*)(qp + 32 * ks + 4);
            short8 fr;
            fr[0]=(short)f2bf(a[0]); fr[1]=(short)f2bf(a[1]);
            fr[2]=(short)f2bf(a[2]); fr[3]=(short)f2bf(a[3]);
            fr[4]=(short)f2bf(b[0]); fr[5]=(short)f2bf(b[1]);
            fr[6]=(short)f2bf(b[2]); fr[7]=(short)f2bf(b[3]);
            qa[fq][ks] = fr;
        }
    }

    floatx4 acc[2][8];
#pragma unroll
    for (int i = 0; i < 2; ++i)
#pragma unroll
        for (int j = 0; j < 8; ++j) { floatx4 z = {0.f,0.f,0.f,0.f}; acc[i][j] = z; }
    float dacc[8];
#pragma unroll
    for (int i = 0; i < 8; ++i) dacc[i] = 0.f;

    const int ntiles = (hEnd > h0) ? (int)((hEnd - h0 + BH - 1) / BH) : 0;

    if (ntiles > 0) {
        // ---- prologue: stage tile 0 into buf 0 ----
        stage_tile_async(Kg, Vg, h0, wid, lane, K_lds[0], V_lds[0]);
        __syncthreads();   // vmcnt(0) drain + barrier

        int cur = 0;
        for (int t = 0; t < ntiles; ++t) {
            const long hb = h0 + (long)t * BH;
            const bool pf = (t + 1 < ntiles);

            // ---- mask(t): issued FIRST so its vmcnt wait doesn't drain staging ----
            float mreg[8];
            {
                long hm = hb + 16 * wn + l15; if (hm > (long)NH - 1) hm = (long)NH - 1;
#pragma unroll
                for (int fq = 0; fq < 2; ++fq)
#pragma unroll
                    for (int j = 0; j < 4; ++j)
                        mreg[fq * 4 + j] = Mg[(size_t)(qrow0 + 16 * fq + 4 * g + j) * NH + hm];
            }

            // ---- stage tile t+1 async into the other buffer (zero registers) ----
            if (pf) stage_tile_async(Kg, Vg, hb + BH, wid, lane, K_lds[cur ^ 1], V_lds[cur ^ 1]);

            // ---- S = Q K^T : wave computes 32q x 16h; K read f32 + cvt ----
            const float* Kc = K_lds[cur];
            const int hrow = 16 * wn + l15;                 // local h row for B-frag
            const float* krp = Kc + hrow * DM;
            const int v4s = vswz4(hrow);
            floatx4 sf[2];
            { floatx4 z = {0.f,0.f,0.f,0.f}; sf[0] = z; sf[1] = z; }
#pragma unroll
            for (int ks = 0; ks < 8; ++ks) {
                const int b0 = (32 * ks + 8 * g) ^ v4s;
                floatx4 c0 = *(const floatx4*)(krp + b0);
                floatx4 c1 = *(const floatx4*)(krp + (b0 ^ 4));
                short8 kb;
                kb[0]=(short)f2bf(c0[0]); kb[1]=(short)f2bf(c0[1]);
                kb[2]=(short)f2bf(c0[2]); kb[3]=(short)f2bf(c0[3]);
                kb[4]=(short)f2bf(c1[0]); kb[5]=(short)f2bf(c1[1]);
                kb[6]=(short)f2bf(c1[2]); kb[7]=(short)f2bf(c1[3]);
                sf[0] = MFMA_BF16(qa[0][ks], kb, sf[0]);
                sf[1] = MFMA_BF16(qa[1][ks], kb, sf[1]);
            }

            // ---- w = mask * exp(s/16) ----
            {
                const long h = hb + 16 * wn + l15;
                const bool valid = (h < hEnd);
#pragma unroll
                for (int fq = 0; fq < 2; ++fq)
#pragma unroll
                    for (int j = 0; j < 4; ++j) {
                        const int rloc = 32 * wm + 16 * fq + 4 * g + j;
                        float m = valid ? mreg[fq * 4 + j] : 0.f;
                        float s = sf[fq][j] * 0.0625f;
                        s = (s > 60.f) ? 60.f : s;
                        float w = m * __expf(s);
                        dacc[fq * 4 + j] += w;
                        w_lds[rloc * WSTR + 16 * wn + l15] = f2bf(w);
                    }
            }
            __syncthreads();   // w ready for all waves

            // ---- PV: out(32q x 128d per wave) += w(.,32h) * V(32h,.) ----
            const float* Vc = V_lds[cur];
#pragma unroll
            for (int fd = 0; fd < 8; ++fd) {
                const int dcol = 128 * wn + 16 * fd + l15;
                short8 vb;
#pragma unroll
                for (int i = 0; i < 8; ++i) {
                    const int hl = 8 * g + i;
                    vb[i] = (short)f2bf(Vc[hl * DM + (dcol ^ vswz4(hl))]);
                }
#pragma unroll
                for (int fq = 0; fq < 2; ++fq) {
                    short8 wa = *(const short8*)&w_lds[(32 * wm + 16 * fq + l15) * WSTR + 8 * g];
                    acc[fq][fd] = MFMA_BF16(wa, vb, acc[fq][fd]);
                }
            }
            __syncthreads();   // protect w_lds + buffer flip (drains staging t+1)
            cur ^= 1;
        }
    }

    // ---- den: reduce 16 h-lanes per row; combine wn halves via LDS ----
    __syncthreads();
    float* dshare = (float*)w_lds;   // w_lds dead now
#pragma unroll
    for (int r = 0; r < 8; ++r) {
        float v = dacc[r];
        v += __shfl_xor(v, 1);
        v += __shfl_xor(v, 2);
        v += __shfl_xor(v, 4);
        v += __shfl_xor(v, 8);
        if (l15 == 0) {
            const int fq = r >> 2, j = r & 3;
            dshare[wn * 128 + 32 * wm + 16 * fq + 4 * g + j] = v;
        }
    }
    __syncthreads();
    if (tid < BQ) {
        denW[(size_t)hc * NQ + qbase + tid] = dshare[tid] + dshare[128 + tid];
    }

    // ---- num partial write ----
#pragma unroll
    for (int fq = 0; fq < 2; ++fq)
#pragma unroll
        for (int fd = 0; fd < 8; ++fd)
#pragma unroll
            for (int j = 0; j < 4; ++j) {
                const int qrow = qbase + 32 * wm + 16 * fq + 4 * g + j;
                const int d    = 128 * wn + 16 * fd + l15;
                numW[((size_t)hc * NQ + qrow) * DM + d] = acc[fq][fd][j];
            }
}

__global__ void maskattn_reduce(const float* __restrict__ numW,
                                const float* __restrict__ denW,
                                float* __restrict__ out, int C)
{
    const int q = blockIdx.x;
    const int d = threadIdx.x;
    float sn = 0.f, sd = 0.f;
    for (int c = 0; c < C; ++c) {
        sn += numW[((size_t)c * NQ + q) * DM + d];
        sd += denW[(size_t)c * NQ + q];
    }
    out[(size_t)q * DM + d] = sn / sd;
}

extern "C" void kernel_launch(void* const* d_in, const int* in_sizes, int n_in,
                              void* d_out, int out_size, void* d_ws, size_t ws_size,
                              hipStream_t stream)
{
    const float* Qg = (const float*)d_in[0];
    const float* Kg = (const float*)d_in[1];
    const float* Vg = (const float*)d_in[2];
    const float* Mg = (const float*)d_in[3];
    float* out = (float*)d_out;

    const size_t per_chunk = (size_t)NQ * DM * sizeof(float) + (size_t)NQ * sizeof(float);
    int C = (int)(ws_size / per_chunk);
    if (C > 64) C = 64;
    float* numW;
    float* denW;
    if (C >= 1) {
        numW = (float*)d_ws;
        denW = numW + (size_t)C * NQ * DM;
    } else {
        C = 1;
        numW = out;                  // emergency fallback
        denW = (float*)d_ws;
    }
    const int chB = (NH + BH * C - 1) / (BH * C);
    const int CH = BH * chB;

    maskattn_phase1<<<dim3((NQ / BQ) * C), dim3(512), 0, stream>>>(Qg, Kg, Vg, Mg, numW, denW, CH);
    maskattn_reduce<<<dim3(NQ), dim3(DM), 0, stream>>>(numW, denW, out, C);
}